// Round 20
// baseline (176.262 us; speedup 1.0000x reference)
//
#include <hip/hip_runtime.h>
#include <hip/hip_bf16.h>

#define HCH 256      // hidden channels
#define NPN 8192     // person nodes
#define NJN 8192     // job nodes
#define EAE 262144   // applied edges
#define CAP 96       // fixed bucket capacity (P(deg>96) ~ 1e-20 at lambda=32)

typedef _Float16 f16x8 __attribute__((ext_vector_type(8)));
typedef _Float16 f16x4 __attribute__((ext_vector_type(4)));
typedef float f32x4 __attribute__((ext_vector_type(4)));

typedef __attribute__((address_space(1))) void glb_void;
typedef __attribute__((address_space(3))) void lds_void;

// ---------------- workspace layout (bytes) ----------------
#define WS_CUR   0          // int[8192]  (deg_dst counter)
#define WS_DEG   32768      // int[8192]  (deg_src)
#define WS_CSR2  65536      // int[8192*96] = 3 MB
#define WS_XH    3211264    // f16[8192*256] = 4 MB
#define WS_ZH    7405568    // f16[8192*256]
#define WS_GH    11599872   // f16[8192*256]
#define WS_WHT   15794176   // f16[256*256]

// k_init: blocks 0..63 zero cur+deg_src; 64..319 WhT; 320..2367 Xh = f16(x)
__global__ void k_init(int* __restrict__ cnt, const float* __restrict__ W,
                       _Float16* __restrict__ WhT, const float* __restrict__ x,
                       _Float16* __restrict__ Xh) {
    int bid = blockIdx.x, t = threadIdx.x;
    if (bid < 64) {
        cnt[bid * 256 + t] = 0;
    } else if (bid < 320) {
        int idx = (bid - 64) * 256 + t;  // 65536
        int n = idx >> 8, k = idx & 255;
        WhT[idx] = (_Float16)W[k * HCH + n];
    } else {
        int i = ((bid - 320) * 256 + t) * 4;  // 2M elems, 4/thread
        float4 v = *(const float4*)(x + i);
        f16x4 h;
        h[0] = (_Float16)v.x; h[1] = (_Float16)v.y;
        h[2] = (_Float16)v.z; h[3] = (_Float16)v.w;
        *(f16x4*)(Xh + i) = h;
    }
}

// k_edge: fused degree-count + bucket (no scan needed with fixed CAP)
__global__ void k_edge(const int* __restrict__ row, const int* __restrict__ col,
                       int* __restrict__ deg_src, int* __restrict__ cur,
                       int* __restrict__ csr2) {
    int e = blockIdx.x * 256 + threadIdx.x;
    int r = row[e], c = col[e];
    atomicAdd(&deg_src[r], 1);
    int p = atomicAdd(&cur[c], 1);
    if (p < CAP) csr2[c * CAP + p] = r;
}

// k_agg: Zh[j][:] = rsqrt(deg_dst[j]) * sum_e rsqrt(deg_src[s_e]) * Xh[s_e][:]
__global__ __launch_bounds__(64)
void k_agg(const _Float16* __restrict__ Xh, const int* __restrict__ csr2,
           const int* __restrict__ cur, const int* __restrict__ deg_src,
           _Float16* __restrict__ Zh) {
    int j = blockIdx.x;
    int t = threadIdx.x;  // 0..63, owns channels 4t..4t+3
    int degt = cur[j];
    int deg = degt > CAP ? CAP : degt;

    __shared__ int   sidx[CAP];
    __shared__ float sw[CAP];
    for (int b = t; b < deg; b += 64) {
        int s = csr2[j * CAP + b];
        sidx[b] = s;
        sw[b] = rsqrtf((float)deg_src[s]);
    }
    __syncthreads();

    float a0 = 0.f, a1 = 0.f, a2 = 0.f, a3 = 0.f;
    const _Float16* xb = Xh + t * 4;
    int e = 0;
    for (; e + 4 <= deg; e += 4) {
        int s0 = sidx[e], s1 = sidx[e + 1], s2 = sidx[e + 2], s3 = sidx[e + 3];
        float w0 = sw[e], w1 = sw[e + 1], w2 = sw[e + 2], w3 = sw[e + 3];
        f16x4 v0 = *(const f16x4*)(xb + (size_t)s0 * HCH);
        f16x4 v1 = *(const f16x4*)(xb + (size_t)s1 * HCH);
        f16x4 v2 = *(const f16x4*)(xb + (size_t)s2 * HCH);
        f16x4 v3 = *(const f16x4*)(xb + (size_t)s3 * HCH);
        a0 += w0 * (float)v0[0] + w1 * (float)v1[0] + w2 * (float)v2[0] + w3 * (float)v3[0];
        a1 += w0 * (float)v0[1] + w1 * (float)v1[1] + w2 * (float)v2[1] + w3 * (float)v3[1];
        a2 += w0 * (float)v0[2] + w1 * (float)v1[2] + w2 * (float)v2[2] + w3 * (float)v3[2];
        a3 += w0 * (float)v0[3] + w1 * (float)v1[3] + w2 * (float)v2[3] + w3 * (float)v3[3];
    }
    for (; e < deg; e++) {
        int s0 = sidx[e];
        float w0 = sw[e];
        f16x4 v0 = *(const f16x4*)(xb + (size_t)s0 * HCH);
        a0 += w0 * (float)v0[0]; a1 += w0 * (float)v0[1];
        a2 += w0 * (float)v0[2]; a3 += w0 * (float)v0[3];
    }
    f16x4 out;
    if (degt > 0) {
        float dd = rsqrtf((float)degt);
        out[0] = (_Float16)(a0 * dd); out[1] = (_Float16)(a1 * dd);
        out[2] = (_Float16)(a2 * dd); out[3] = (_Float16)(a3 * dd);
    } else {
        out[0] = out[1] = out[2] = out[3] = (_Float16)0.f;
    }
    *(f16x4*)(Zh + (size_t)j * HCH + t * 4) = out;
}

// ---------------- gemm1: Gh = Zh @ WhT^T + b  (64x128 tiles, dbuf 2-phase) ---
template <int TM, int TN>
__global__ __launch_bounds__(256, 2)
void k_gemm(const _Float16* __restrict__ A, const _Float16* __restrict__ Bt,
            const float* __restrict__ bias, _Float16* __restrict__ Cout, int Ncols) {
    constexpr int WM = TM / 2, WN = TN / 2;
    constexpr int MR = WM / 16, NR = WN / 16;
    constexpr int CHA = TM * 8 / 256;
    constexpr int CHB = TN * 8 / 256;
    constexpr int BOFF = TM * 128;

    __shared__ _Float16 sm[2][(TM + TN) * 64];

    int tid = threadIdx.x;
    int wid = tid >> 6, lane = tid & 63;

    int brow = blockIdx.y * TM;
    int bcol = blockIdx.x * TN;
    int wrow = (wid >> 1) * WM;
    int wcol = (wid & 1) * WN;

    f32x4 acc[MR][NR] = {};

    int lr = lane & 15;
    int kq = lane >> 4;

    auto stage = [&](int t, int b) {
        int k0 = t * 64;
#pragma unroll
        for (int i = 0; i < CHA; i++) {
            int wc0 = i * 256 + wid * 64;
            int c = wc0 + lane;
            int r = c >> 3, cc = c & 7;
            const char* ga = (const char*)A +
                (size_t)(brow + r) * (HCH * 2) + (size_t)(k0 + cc * 8) * 2;
            __builtin_amdgcn_global_load_lds(
                (glb_void*)ga, (lds_void*)((char*)sm[b] + wc0 * 16), 16, 0, 0);
        }
#pragma unroll
        for (int i = 0; i < CHB; i++) {
            int wc0 = i * 256 + wid * 64;
            int c = wc0 + lane;
            int r = c >> 3, cc = c & 7;
            const char* gb = (const char*)Bt +
                (size_t)(bcol + r) * (HCH * 2) + (size_t)(k0 + cc * 8) * 2;
            __builtin_amdgcn_global_load_lds(
                (glb_void*)gb, (lds_void*)((char*)sm[b] + BOFF + wc0 * 16), 16, 0, 0);
        }
    };

    stage(0, 0);
    __syncthreads();

    constexpr int NT = HCH / 64;
#pragma unroll
    for (int t = 0; t < NT; t++) {
        int cur = t & 1;
        if (t + 1 < NT) stage(t + 1, cur ^ 1);
        const char* base = (const char*)sm[cur];
#pragma unroll
        for (int kk = 0; kk < 64; kk += 32) {
            f16x8 af[MR], bfr[NR];
            int kbyte = (kk + kq * 8) * 2;
#pragma unroll
            for (int m = 0; m < MR; m++) {
                int r = wrow + m * 16 + lr;
                af[m] = *(const f16x8*)(base + r * 128 + kbyte);
            }
#pragma unroll
            for (int n = 0; n < NR; n++) {
                int r = wcol + n * 16 + lr;
                bfr[n] = *(const f16x8*)(base + BOFF + r * 128 + kbyte);
            }
#pragma unroll
            for (int m = 0; m < MR; m++)
#pragma unroll
                for (int n = 0; n < NR; n++)
                    acc[m][n] = __builtin_amdgcn_mfma_f32_16x16x32_f16(
                        af[m], bfr[n], acc[m][n], 0, 0, 0);
        }
        __syncthreads();
    }

    int rq = lane >> 4;
#pragma unroll
    for (int m = 0; m < MR; m++) {
#pragma unroll
        for (int n = 0; n < NR; n++) {
#pragma unroll
            for (int j = 0; j < 4; j++) {
                int gr = brow + wrow + m * 16 + rq * 4 + j;
                int gc = bcol + wcol + n * 16 + lr;
                float v = acc[m][n][j] + bias[gc];
                Cout[(size_t)gr * Ncols + gc] = (_Float16)v;
            }
        }
    }
}

// ---------------- gemm2: scores = sigmoid(Xh @ Gh^T)  [8192,8192] fp32 ------
// v7 = r13 with smB/stageB DELETED: B-fragments load DIRECT from global
// (Gh panel is L2-resident; the 4 kq-lanes cover 64B contiguous per row ->
// zero fetch waste; 4x L2 re-read = 19.5 TB/s < 34.5 ceiling). With B out of
// LDS there is NO shared state in the main loop -> ZERO barriers: each wave
// free-runs its own pipeline {16 B-loads -> MFMA -> wave-private smC ->
// sigmoid -> nt-store}, waves desync across tiles, store pipe stays fed
// (attacks the 54%-of-fill-BW store duty cycle).
#define G2_NW 32
__global__ __launch_bounds__(512, 1)
void k_gemm2(const _Float16* __restrict__ A, const _Float16* __restrict__ Bt,
             float* __restrict__ C) {
    __shared__ _Float16 smA[128 * HCH];      // 64KB
    __shared__ float    smC[128 * 64];       // 32KB  (total 96KB)

    int tid = threadIdx.x;
    int wid = tid >> 6, lane = tid & 63;
    int lr = lane & 15, kq = lane >> 4;

    int id = blockIdx.x;                 // 0..255
    int xcd = id & 7, slot = id >> 3;
    int cg2 = xcd >> 1;                  // col-group 0..3 (2048 cols each)
    int strip = slot + (xcd & 1) * 32;   // row strip 0..63
    int brow = strip * 128;
    int bcol0 = cg2 * (64 * G2_NW);

    int wrow = (wid >> 1) * 32;          // 4 M-waves
    int wcol = (wid & 1) * 32;           // 2 N-waves

    // stage A strip: 128 rows x 32 chunks(16B), source-preswizzled (rule 21)
#pragma unroll
    for (int i = 0; i < 8; i++) {
        int wc0 = i * 512 + wid * 64;
        int c = wc0 + lane;
        int r = c >> 5, q = c & 31;
        int j = q ^ (r & 7);
        const char* ga = (const char*)(A + (size_t)(brow + r) * HCH + j * 8);
        __builtin_amdgcn_global_load_lds(
            (glb_void*)ga, (lds_void*)((char*)smA + wc0 * 16), 16, 0, 0);
    }
    __syncthreads();     // prologue drain: A resident (only barrier in kernel)

    // ---- fill register-resident A fragments (once, reused for all tiles) ----
    const char* sA = (const char*)smA;
    f16x8 areg[2][8];
#pragma unroll
    for (int m = 0; m < 2; m++) {
#pragma unroll
        for (int ks = 0; ks < 8; ks++) {
            int r = wrow + m * 16 + lr;
            int sb = ks * 4 + kq;
            areg[m][ks] = *(const f16x8*)(sA + r * 512 + ((sb ^ (r & 7)) << 4));
        }
    }

    for (int t = 0; t < G2_NW; t++) {
        // ---- B fragments direct from global (16 loads, all independent) ----
        int rowb = bcol0 + t * 64 + wcol;
        f16x8 bf[2][8];
#pragma unroll
        for (int n = 0; n < 2; n++)
#pragma unroll
            for (int ks = 0; ks < 8; ks++)
                bf[n][ks] = *(const f16x8*)(Bt +
                    (size_t)(rowb + n * 16 + lr) * HCH + (ks * 4 + kq) * 8);

        f32x4 acc[2][2] = {};
        __builtin_amdgcn_s_setprio(1);
#pragma unroll
        for (int ks = 0; ks < 8; ks++)
#pragma unroll
            for (int m = 0; m < 2; m++)
#pragma unroll
                for (int n = 0; n < 2; n++)
                    acc[m][n] = __builtin_amdgcn_mfma_f32_16x16x32_f16(
                        bf[n][ks], areg[m][ks], acc[m][n], 0, 0, 0);
        __builtin_amdgcn_s_setprio(0);

        // ---- stage acc into this wave's own swizzled smC region ----
#pragma unroll
        for (int m = 0; m < 2; m++) {
#pragma unroll
            for (int n = 0; n < 2; n++) {
                int row = wrow + m * 16 + lr;
                int ch = ((wcol + n * 16) >> 2) + kq;   // 16B chunk 0..15
                int sc = ch ^ (row & 7);
                *(f32x4*)(smC + row * 64 + sc * 4) = acc[m][n];
            }
        }
        // wave-local RAW: compiler orders via lgkmcnt; no barrier needed.

        // ---- per-wave readback + sigmoid + whole-line stores ----
        int bcol = bcol0 + t * 64;
        int ch = (wcol >> 2) + (lane & 7);   // this lane's chunk (8 per wave)
#pragma unroll
        for (int p = 0; p < 4; p++) {
            int row = wrow + p * 8 + (lane >> 3);   // 8 rows per iter
            int sc = ch ^ (row & 7);
            f32x4 v = *(const f32x4*)(smC + row * 64 + sc * 4);
            f32x4 o;
#pragma unroll
            for (int j = 0; j < 4; j++) {
                float e = __expf(-v[j]);
                o[j] = __builtin_amdgcn_rcpf(1.f + e);
            }
            __builtin_nontemporal_store(
                o, (f32x4*)(C + (size_t)(brow + row) * NJN + bcol + ch * 4));
        }
        // no sync: next tile's B-loads issue immediately; stores drain behind.
    }
}

extern "C" void kernel_launch(void* const* d_in, const int* in_sizes, int n_in,
                              void* d_out, int out_size, void* d_ws, size_t ws_size,
                              hipStream_t stream) {
    const float* x_person = (const float*)d_in[0];
    const int*   ei_app   = (const int*)d_in[3];   // [2, EA]
    const float* W_aj     = (const float*)d_in[6];
    const float* b_aj     = (const float*)d_in[7];

    const int* erow = ei_app;         // src (person)
    const int* ecol = ei_app + EAE;   // dst (job)

    char* w = (char*)d_ws;
    int*      cur     = (int*)(w + WS_CUR);
    int*      deg_src = (int*)(w + WS_DEG);
    int*      csr2    = (int*)(w + WS_CSR2);
    _Float16* Xh      = (_Float16*)(w + WS_XH);
    _Float16* Zh      = (_Float16*)(w + WS_ZH);
    _Float16* Gh      = (_Float16*)(w + WS_GH);
    _Float16* WhT     = (_Float16*)(w + WS_WHT);

    // 1. zero counters + f16 conversions (all independent)
    k_init<<<2368, 256, 0, stream>>>(cur, W_aj, WhT, x_person, Xh);
    // 2. fused degree-count + bucket (fixed-capacity CSR, no scan)
    k_edge<<<EAE / 256, 256, 0, stream>>>(erow, ecol, deg_src, cur, csr2);
    // 3. aggregate
    k_agg<<<NJN, 64, 0, stream>>>(Xh, csr2, cur, deg_src, Zh);
    // 4. job_emb: Gh = Zh @ W + b
    {
        dim3 grid(HCH / 128, NJN / 64);
        k_gemm<64, 128><<<grid, 256, 0, stream>>>(Zh, WhT, b_aj, Gh, HCH);
    }
    // 5. scores = sigmoid(Xh @ Gh^T)  — barrier-free free-running waves
    k_gemm2<<<256, 512, 0, stream>>>(Xh, Gh, (float*)d_out);
}

// Round 21
// 125.991 us; speedup vs baseline: 1.3990x; 1.3990x over previous
//
#include <hip/hip_runtime.h>
#include <hip/hip_bf16.h>

#define HCH 256      // hidden channels
#define NPN 8192     // person nodes
#define NJN 8192     // job nodes
#define EAE 262144   // applied edges
#define CAP 96       // fixed bucket capacity (P(deg>96) ~ 1e-20 at lambda=32)

typedef _Float16 f16x8 __attribute__((ext_vector_type(8)));
typedef _Float16 f16x4 __attribute__((ext_vector_type(4)));
typedef float f32x4 __attribute__((ext_vector_type(4)));

typedef __attribute__((address_space(1))) void glb_void;
typedef __attribute__((address_space(3))) void lds_void;

// ---------------- workspace layout (bytes) ----------------
#define WS_CUR   0          // int[8192]  (deg_dst counter)
#define WS_DEG   32768      // int[8192]  (deg_src)
#define WS_CSR2  65536      // int[8192*96] = 3 MB
#define WS_XH    3211264    // f16[8192*256] = 4 MB
#define WS_ZH    7405568    // f16[8192*256]
#define WS_GH    11599872   // f16[8192*256]
#define WS_WHT   15794176   // f16[256*256]

// k_init: blocks 0..63 zero cur+deg_src; 64..319 WhT; 320..2367 Xh = f16(x)
__global__ void k_init(int* __restrict__ cnt, const float* __restrict__ W,
                       _Float16* __restrict__ WhT, const float* __restrict__ x,
                       _Float16* __restrict__ Xh) {
    int bid = blockIdx.x, t = threadIdx.x;
    if (bid < 64) {
        cnt[bid * 256 + t] = 0;
    } else if (bid < 320) {
        int idx = (bid - 64) * 256 + t;  // 65536
        int n = idx >> 8, k = idx & 255;
        WhT[idx] = (_Float16)W[k * HCH + n];
    } else {
        int i = ((bid - 320) * 256 + t) * 4;  // 2M elems, 4/thread
        float4 v = *(const float4*)(x + i);
        f16x4 h;
        h[0] = (_Float16)v.x; h[1] = (_Float16)v.y;
        h[2] = (_Float16)v.z; h[3] = (_Float16)v.w;
        *(f16x4*)(Xh + i) = h;
    }
}

// k_edge: fused degree-count + bucket (no scan needed with fixed CAP)
__global__ void k_edge(const int* __restrict__ row, const int* __restrict__ col,
                       int* __restrict__ deg_src, int* __restrict__ cur,
                       int* __restrict__ csr2) {
    int e = blockIdx.x * 256 + threadIdx.x;
    int r = row[e], c = col[e];
    atomicAdd(&deg_src[r], 1);
    int p = atomicAdd(&cur[c], 1);
    if (p < CAP) csr2[c * CAP + p] = r;
}

// k_agg: Zh[j][:] = rsqrt(deg_dst[j]) * sum_e rsqrt(deg_src[s_e]) * Xh[s_e][:]
__global__ __launch_bounds__(64)
void k_agg(const _Float16* __restrict__ Xh, const int* __restrict__ csr2,
           const int* __restrict__ cur, const int* __restrict__ deg_src,
           _Float16* __restrict__ Zh) {
    int j = blockIdx.x;
    int t = threadIdx.x;  // 0..63, owns channels 4t..4t+3
    int degt = cur[j];
    int deg = degt > CAP ? CAP : degt;

    __shared__ int   sidx[CAP];
    __shared__ float sw[CAP];
    for (int b = t; b < deg; b += 64) {
        int s = csr2[j * CAP + b];
        sidx[b] = s;
        sw[b] = rsqrtf((float)deg_src[s]);
    }
    __syncthreads();

    float a0 = 0.f, a1 = 0.f, a2 = 0.f, a3 = 0.f;
    const _Float16* xb = Xh + t * 4;
    int e = 0;
    for (; e + 4 <= deg; e += 4) {
        int s0 = sidx[e], s1 = sidx[e + 1], s2 = sidx[e + 2], s3 = sidx[e + 3];
        float w0 = sw[e], w1 = sw[e + 1], w2 = sw[e + 2], w3 = sw[e + 3];
        f16x4 v0 = *(const f16x4*)(xb + (size_t)s0 * HCH);
        f16x4 v1 = *(const f16x4*)(xb + (size_t)s1 * HCH);
        f16x4 v2 = *(const f16x4*)(xb + (size_t)s2 * HCH);
        f16x4 v3 = *(const f16x4*)(xb + (size_t)s3 * HCH);
        a0 += w0 * (float)v0[0] + w1 * (float)v1[0] + w2 * (float)v2[0] + w3 * (float)v3[0];
        a1 += w0 * (float)v0[1] + w1 * (float)v1[1] + w2 * (float)v2[1] + w3 * (float)v3[1];
        a2 += w0 * (float)v0[2] + w1 * (float)v1[2] + w2 * (float)v2[2] + w3 * (float)v3[2];
        a3 += w0 * (float)v0[3] + w1 * (float)v1[3] + w2 * (float)v2[3] + w3 * (float)v3[3];
    }
    for (; e < deg; e++) {
        int s0 = sidx[e];
        float w0 = sw[e];
        f16x4 v0 = *(const f16x4*)(xb + (size_t)s0 * HCH);
        a0 += w0 * (float)v0[0]; a1 += w0 * (float)v0[1];
        a2 += w0 * (float)v0[2]; a3 += w0 * (float)v0[3];
    }
    f16x4 out;
    if (degt > 0) {
        float dd = rsqrtf((float)degt);
        out[0] = (_Float16)(a0 * dd); out[1] = (_Float16)(a1 * dd);
        out[2] = (_Float16)(a2 * dd); out[3] = (_Float16)(a3 * dd);
    } else {
        out[0] = out[1] = out[2] = out[3] = (_Float16)0.f;
    }
    *(f16x4*)(Zh + (size_t)j * HCH + t * 4) = out;
}

// ---------------- gemm1: Gh = Zh @ WhT^T + b  (64x128 tiles, dbuf 2-phase) ---
template <int TM, int TN>
__global__ __launch_bounds__(256, 2)
void k_gemm(const _Float16* __restrict__ A, const _Float16* __restrict__ Bt,
            const float* __restrict__ bias, _Float16* __restrict__ Cout, int Ncols) {
    constexpr int WM = TM / 2, WN = TN / 2;
    constexpr int MR = WM / 16, NR = WN / 16;
    constexpr int CHA = TM * 8 / 256;
    constexpr int CHB = TN * 8 / 256;
    constexpr int BOFF = TM * 128;

    __shared__ _Float16 sm[2][(TM + TN) * 64];

    int tid = threadIdx.x;
    int wid = tid >> 6, lane = tid & 63;

    int brow = blockIdx.y * TM;
    int bcol = blockIdx.x * TN;
    int wrow = (wid >> 1) * WM;
    int wcol = (wid & 1) * WN;

    f32x4 acc[MR][NR] = {};

    int lr = lane & 15;
    int kq = lane >> 4;

    auto stage = [&](int t, int b) {
        int k0 = t * 64;
#pragma unroll
        for (int i = 0; i < CHA; i++) {
            int wc0 = i * 256 + wid * 64;
            int c = wc0 + lane;
            int r = c >> 3, cc = c & 7;
            const char* ga = (const char*)A +
                (size_t)(brow + r) * (HCH * 2) + (size_t)(k0 + cc * 8) * 2;
            __builtin_amdgcn_global_load_lds(
                (glb_void*)ga, (lds_void*)((char*)sm[b] + wc0 * 16), 16, 0, 0);
        }
#pragma unroll
        for (int i = 0; i < CHB; i++) {
            int wc0 = i * 256 + wid * 64;
            int c = wc0 + lane;
            int r = c >> 3, cc = c & 7;
            const char* gb = (const char*)Bt +
                (size_t)(bcol + r) * (HCH * 2) + (size_t)(k0 + cc * 8) * 2;
            __builtin_amdgcn_global_load_lds(
                (glb_void*)gb, (lds_void*)((char*)sm[b] + BOFF + wc0 * 16), 16, 0, 0);
        }
    };

    stage(0, 0);
    __syncthreads();

    constexpr int NT = HCH / 64;
#pragma unroll
    for (int t = 0; t < NT; t++) {
        int cur = t & 1;
        if (t + 1 < NT) stage(t + 1, cur ^ 1);
        const char* base = (const char*)sm[cur];
#pragma unroll
        for (int kk = 0; kk < 64; kk += 32) {
            f16x8 af[MR], bfr[NR];
            int kbyte = (kk + kq * 8) * 2;
#pragma unroll
            for (int m = 0; m < MR; m++) {
                int r = wrow + m * 16 + lr;
                af[m] = *(const f16x8*)(base + r * 128 + kbyte);
            }
#pragma unroll
            for (int n = 0; n < NR; n++) {
                int r = wcol + n * 16 + lr;
                bfr[n] = *(const f16x8*)(base + BOFF + r * 128 + kbyte);
            }
#pragma unroll
            for (int m = 0; m < MR; m++)
#pragma unroll
                for (int n = 0; n < NR; n++)
                    acc[m][n] = __builtin_amdgcn_mfma_f32_16x16x32_f16(
                        af[m], bfr[n], acc[m][n], 0, 0, 0);
        }
        __syncthreads();
    }

    int rq = lane >> 4;
#pragma unroll
    for (int m = 0; m < MR; m++) {
#pragma unroll
        for (int n = 0; n < NR; n++) {
#pragma unroll
            for (int j = 0; j < 4; j++) {
                int gr = brow + wrow + m * 16 + rq * 4 + j;
                int gc = bcol + wcol + n * 16 + lr;
                float v = acc[m][n][j] + bias[gc];
                Cout[(size_t)gr * Ncols + gc] = (_Float16)v;
            }
        }
    }
}

// ---------------- gemm2: scores = sigmoid(Xh @ Gh^T)  [8192,8192] fp32 ------
// r13 EXACT (champion: gemm2 ~72.6us, total 126.2): K-resident A-stationary,
// register-resident A (4Mx2N wave grid), dbuf smB, barrier-free per-wave smC
// epilogue, counted vmcnt(4), setprio around compute.
#define G2_NW 32
__global__ __launch_bounds__(512, 1)
void k_gemm2(const _Float16* __restrict__ A, const _Float16* __restrict__ Bt,
             float* __restrict__ C) {
    __shared__ _Float16 smA[128 * HCH];      // 64KB
    __shared__ _Float16 smB[2][64 * HCH];    // 2 x 32KB
    __shared__ float    smC[128 * 64];       // 32KB  (total 160KB)

    int tid = threadIdx.x;
    int wid = tid >> 6, lane = tid & 63;
    int lr = lane & 15, kq = lane >> 4;

    int id = blockIdx.x;                 // 0..255
    int xcd = id & 7, slot = id >> 3;
    int cg2 = xcd >> 1;                  // col-group 0..3 (2048 cols each)
    int strip = slot + (xcd & 1) * 32;   // row strip 0..63
    int brow = strip * 128;
    int bcol0 = cg2 * (64 * G2_NW);

    int wrow = (wid >> 1) * 32;          // 4 M-waves
    int wcol = (wid & 1) * 32;           // 2 N-waves

    // stage A strip: 128 rows x 32 chunks(16B), source-preswizzled (rule 21)
#pragma unroll
    for (int i = 0; i < 8; i++) {
        int wc0 = i * 512 + wid * 64;
        int c = wc0 + lane;
        int r = c >> 5, q = c & 31;
        int j = q ^ (r & 7);
        const char* ga = (const char*)(A + (size_t)(brow + r) * HCH + j * 8);
        __builtin_amdgcn_global_load_lds(
            (glb_void*)ga, (lds_void*)((char*)smA + wc0 * 16), 16, 0, 0);
    }
    auto stageB = [&](int t, int b) {
#pragma unroll
        for (int i = 0; i < 4; i++) {
            int wc0 = i * 512 + wid * 64;
            int c = wc0 + lane;
            int r = c >> 5, q = c & 31;
            int j = q ^ (r & 7);
            const char* gb = (const char*)(Bt +
                (size_t)(bcol0 + t * 64 + r) * HCH + j * 8);
            __builtin_amdgcn_global_load_lds(
                (glb_void*)gb, (lds_void*)((char*)smB[b] + wc0 * 16), 16, 0, 0);
        }
    };
    stageB(0, 0);
    __syncthreads();     // prologue drain: A + B0 resident

    // ---- fill register-resident A fragments (once, reused for all tiles) ----
    const char* sA = (const char*)smA;
    f16x8 areg[2][8];
#pragma unroll
    for (int m = 0; m < 2; m++) {
#pragma unroll
        for (int ks = 0; ks < 8; ks++) {
            int r = wrow + m * 16 + lr;
            int sb = ks * 4 + kq;
            areg[m][ks] = *(const f16x8*)(sA + r * 512 + ((sb ^ (r & 7)) << 4));
        }
    }

    for (int t = 0; t < G2_NW; t++) {
        int cb = t & 1;
        if (t + 1 < G2_NW) stageB(t + 1, cb ^ 1);
        __builtin_amdgcn_sched_barrier(0);
        const char* sB = (const char*)smB[cb];
        f32x4 acc[2][2] = {};
        __builtin_amdgcn_s_setprio(1);
#pragma unroll
        for (int ks = 0; ks < 8; ks++) {
            f16x8 bf2[2];
            int sb = ks * 4 + kq;
#pragma unroll
            for (int n = 0; n < 2; n++) {
                int r = wcol + n * 16 + lr;
                bf2[n] = *(const f16x8*)(sB + r * 512 + ((sb ^ (r & 7)) << 4));
            }
            // swapped operands: out_row = lane&15 (+16m), out_col quad = kq*4
#pragma unroll
            for (int m = 0; m < 2; m++)
#pragma unroll
                for (int n = 0; n < 2; n++)
                    acc[m][n] = __builtin_amdgcn_mfma_f32_16x16x32_f16(
                        bf2[n], areg[m][ks], acc[m][n], 0, 0, 0);
        }
        __builtin_amdgcn_s_setprio(0);

        // ---- stage acc into this wave's own swizzled smC region ----
#pragma unroll
        for (int m = 0; m < 2; m++) {
#pragma unroll
            for (int n = 0; n < 2; n++) {
                int row = wrow + m * 16 + lr;
                int ch = ((wcol + n * 16) >> 2) + kq;   // 16B chunk 0..15
                int sc = ch ^ (row & 7);
                *(f32x4*)(smC + row * 64 + sc * 4) = acc[m][n];
            }
        }
        // NO barrier: readback is wave-local (same wave wrote these rows).

        // ---- per-wave readback + sigmoid + whole-line stores ----
        int bcol = bcol0 + t * 64;
        int ch = (wcol >> 2) + (lane & 7);   // this lane's chunk (8 per wave)
#pragma unroll
        for (int p = 0; p < 4; p++) {
            int row = wrow + p * 8 + (lane >> 3);   // 8 rows per iter
            int sc = ch ^ (row & 7);
            f32x4 v = *(const f32x4*)(smC + row * 64 + sc * 4);
            f32x4 o;
#pragma unroll
            for (int j = 0; j < 4; j++) {
                float e = __expf(-v[j]);
                o[j] = __builtin_amdgcn_rcpf(1.f + e);
            }
            __builtin_nontemporal_store(
                o, (f32x4*)(C + (size_t)(brow + row) * NJN + bcol + ch * 4));
        }

        if (t + 1 < G2_NW) {
            // counted drain: stage loads done (next buf resident), this
            // tile's stores left in flight (T4: never vmcnt(0) in loop)
            __builtin_amdgcn_sched_barrier(0);
            asm volatile("s_waitcnt vmcnt(4)" ::: "memory");
            __builtin_amdgcn_s_barrier();
            __builtin_amdgcn_sched_barrier(0);
        }
    }
}

extern "C" void kernel_launch(void* const* d_in, const int* in_sizes, int n_in,
                              void* d_out, int out_size, void* d_ws, size_t ws_size,
                              hipStream_t stream) {
    const float* x_person = (const float*)d_in[0];
    const int*   ei_app   = (const int*)d_in[3];   // [2, EA]
    const float* W_aj     = (const float*)d_in[6];
    const float* b_aj     = (const float*)d_in[7];

    const int* erow = ei_app;         // src (person)
    const int* ecol = ei_app + EAE;   // dst (job)

    char* w = (char*)d_ws;
    int*      cur     = (int*)(w + WS_CUR);
    int*      deg_src = (int*)(w + WS_DEG);
    int*      csr2    = (int*)(w + WS_CSR2);
    _Float16* Xh      = (_Float16*)(w + WS_XH);
    _Float16* Zh      = (_Float16*)(w + WS_ZH);
    _Float16* Gh      = (_Float16*)(w + WS_GH);
    _Float16* WhT     = (_Float16*)(w + WS_WHT);

    // 1. zero counters + f16 conversions (all independent)
    k_init<<<2368, 256, 0, stream>>>(cur, W_aj, WhT, x_person, Xh);
    // 2. fused degree-count + bucket (fixed-capacity CSR, no scan)
    k_edge<<<EAE / 256, 256, 0, stream>>>(erow, ecol, deg_src, cur, csr2);
    // 3. aggregate
    k_agg<<<NJN, 64, 0, stream>>>(Xh, csr2, cur, deg_src, Zh);
    // 4. job_emb: Gh = Zh @ W + b
    {
        dim3 grid(HCH / 128, NJN / 64);
        k_gemm<64, 128><<<grid, 256, 0, stream>>>(Zh, WhT, b_aj, Gh, HCH);
    }
    // 5. scores = sigmoid(Xh @ Gh^T)
    k_gemm2<<<256, 512, 0, stream>>>(Xh, Gh, (float*)d_out);
}